// Round 1
// baseline (850.664 us; speedup 1.0000x reference)
//
#include <hip/hip_runtime.h>

// Problem dims
#define BB 64
#define SS 2048
#define INDIM 256
#define HH 512
#define EE 256
#define OUTD 32000

typedef __attribute__((ext_vector_type(8))) short short8;
typedef __attribute__((ext_vector_type(4))) float floatx4;

// ---- helpers ----
__device__ __forceinline__ unsigned short f2bf(float f) {
  unsigned u = __float_as_uint(f);
  return (unsigned short)((u + 0x7FFFu + ((u >> 16) & 1u)) >> 16);  // RNE
}
__device__ __forceinline__ unsigned pk2(float a, float b) {
  return (unsigned)f2bf(a) | ((unsigned)f2bf(b) << 16);
}
__device__ __forceinline__ float fast_tanh(float x) {
  // tanh(x) = 1 - 2/(exp2(2x*log2e)+1); saturates correctly at +-inf
  float e = __builtin_amdgcn_exp2f(x * 2.8853900817779268f);
  return 1.0f - 2.0f * __builtin_amdgcn_rcpf(e + 1.0f);
}
__device__ __forceinline__ float fast_sigmoid(float x) {
  float e = __builtin_amdgcn_exp2f(-x * 1.4426950408889634f);
  return __builtin_amdgcn_rcpf(1.0f + e);
}

// ws layout (bytes)
#define WS_W1T 0         // 256x512 bf16 (W1 transposed) : 262144
#define WS_HB  262144    // 64x256 f32  hidden@W2 + W1_b : 65536
#define WS_CTX 327680    // 64x512 f32  context (atomic) : 131072
#define WS_R   458752    // 64x512 f32  reset gate       : 131072
#define WS_Z   589824    // 64x512 f32  update gate      : 131072
#define WS_RH  720896    // 64x512 f32  r*hidden         : 131072

// ---- prep: transpose+convert W1 -> bf16 [e][k]; zero ctx; zero out-proj region ----
__global__ void k_prep(const float* __restrict__ W1, unsigned short* __restrict__ W1t,
                       float* __restrict__ ctx, float* __restrict__ out) {
  int idx = blockIdx.x * 256 + threadIdx.x;
  if (idx < HH * EE) {                       // idx = k*256 + e (coalesced read)
    int k = idx >> 8, e = idx & 255;
    W1t[e * HH + k] = f2bf(W1[idx]);
  }
  if (idx < BB * HH) ctx[idx] = 0.0f;
  if (idx < BB * OUTD) out[idx] = 0.0f;      // atomic target must start at 0
}

// ---- hb[b][e] = W1_b[e] + hidden[b]@W2[:,e] ----
__global__ void k_hb(const float* __restrict__ hidden, const float* __restrict__ W2,
                     const float* __restrict__ W1b, float* __restrict__ hb) {
  int b = blockIdx.x, e = threadIdx.x;
  float acc = W1b[e];
  for (int h = 0; h < HH; ++h)
    acc += hidden[b * HH + h] * W2[h * EE + e];   // hidden: s_load (uniform), W2: coalesced
  hb[b * EE + e] = acc;
}

// ---- scores: per 128-row tile, C = enc@W1 (bf16 MFMA), score = sum_e tanh(C+hb)*v ----
// grid 1024 (M/128), block 512 (8 waves as 2(M) x 4(N)), N=256 full, K=512 in BK=32 chunks
#define LDK 40   // 32 k + 8 pad shorts -> 80 B row: 16B-aligned, bank-start rotates (2-way max)
__global__ __launch_bounds__(512) void k_scores(
    const float* __restrict__ enc, const unsigned short* __restrict__ W1t,
    const float* __restrict__ hb, const float* __restrict__ vw,
    float* __restrict__ scores) {
  __shared__ unsigned short As[128 * LDK];
  __shared__ unsigned short Bs[256 * LDK];
  __shared__ float hb_s[EE], v_s[EE];
  __shared__ float red[4 * 128];

  int tid = threadIdx.x;
  int m0 = blockIdx.x * 128;
  int b = m0 >> 11;                // S=2048 per batch; 16 tiles per b
  if (tid < EE) { hb_s[tid] = hb[b * EE + tid]; v_s[tid] = vw[tid]; }

  int lane = tid & 63, wid = tid >> 6;
  int wm = wid >> 2, wn = wid & 3;
  int l15 = lane & 15, quad = lane >> 4;

  floatx4 acc[4][4];
#pragma unroll
  for (int i = 0; i < 4; ++i)
#pragma unroll
    for (int j = 0; j < 4; ++j) acc[i][j] = (floatx4)0.0f;

  for (int kb = 0; kb < 16; ++kb) {
    int k0 = kb * 32;
    // stage A tile: 128 rows x 32 k, fp32 -> bf16
#pragma unroll
    for (int t = 0; t < 2; ++t) {
      int idx = tid + t * 512;          // 1024 float4 chunks
      int row = idx >> 3, kg = idx & 7;
      float4 f = *(const float4*)(enc + (size_t)(m0 + row) * HH + k0 + kg * 4);
      uint2 w; w.x = pk2(f.x, f.y); w.y = pk2(f.z, f.w);
      *(uint2*)(As + row * LDK + kg * 4) = w;
    }
    // stage B tile: 256 e x 32 k (already bf16, [e][k])
#pragma unroll
    for (int t = 0; t < 2; ++t) {
      int idx = tid + t * 512;          // 1024 16B chunks
      int e = idx >> 2, kc = idx & 3;
      *(uint4*)(Bs + e * LDK + kc * 8) = *(const uint4*)(W1t + e * HH + k0 + kc * 8);
    }
    __syncthreads();
    int kk = quad * 8;
    short8 a[4];
#pragma unroll
    for (int i = 0; i < 4; ++i)
      a[i] = *(const short8*)(As + (wm * 64 + i * 16 + l15) * LDK + kk);
#pragma unroll
    for (int j = 0; j < 4; ++j) {
      short8 bfr = *(const short8*)(Bs + (wn * 64 + j * 16 + l15) * LDK + kk);
#pragma unroll
      for (int i = 0; i < 4; ++i)
        acc[i][j] = __builtin_amdgcn_mfma_f32_16x16x32_bf16(a[i], bfr, acc[i][j], 0, 0, 0);
    }
    __syncthreads();
  }

  // epilogue: score[row] = sum_e tanh(C+hb[e])*v[e]; C/D: col=lane&15, row=quad*4+reg
#pragma unroll
  for (int i = 0; i < 4; ++i)
#pragma unroll
    for (int r = 0; r < 4; ++r) {
      float s = 0.0f;
#pragma unroll
      for (int j = 0; j < 4; ++j) {
        int e = wn * 64 + j * 16 + l15;
        s += fast_tanh(acc[i][j][r] + hb_s[e]) * v_s[e];
      }
#pragma unroll
      for (int off = 1; off < 16; off <<= 1) s += __shfl_xor(s, off, 64);
      if (l15 == 0) red[wn * 128 + wm * 64 + i * 16 + quad * 4 + r] = s;
    }
  __syncthreads();
  if (tid < 128) {
    float sc = red[tid] + red[128 + tid] + red[256 + tid] + red[384 + tid];
    scores[b * SS + (m0 & (SS - 1)) + tid] = sc;
  }
}

// ---- softmax over S, in place on scores/attn region ----
__global__ void k_softmax(float* __restrict__ attn) {
  int b = blockIdx.x, tid = threadIdx.x;
  float* p = attn + b * SS;
  float v[8];
#pragma unroll
  for (int i = 0; i < 8; ++i) v[i] = p[tid + i * 256];
  float m = v[0];
#pragma unroll
  for (int i = 1; i < 8; ++i) m = fmaxf(m, v[i]);
#pragma unroll
  for (int off = 1; off < 64; off <<= 1) m = fmaxf(m, __shfl_xor(m, off, 64));
  __shared__ float red[8];
  int lane = tid & 63, w = tid >> 6;
  if (lane == 0) red[w] = m;
  __syncthreads();
  m = fmaxf(fmaxf(red[0], red[1]), fmaxf(red[2], red[3]));
  float s = 0.0f;
#pragma unroll
  for (int i = 0; i < 8; ++i) {
    v[i] = __builtin_amdgcn_exp2f((v[i] - m) * 1.4426950408889634f);
    s += v[i];
  }
#pragma unroll
  for (int off = 1; off < 64; off <<= 1) s += __shfl_xor(s, off, 64);
  if (lane == 0) red[4 + w] = s;
  __syncthreads();
  s = red[4] + red[5] + red[6] + red[7];
  float inv = 1.0f / s;
#pragma unroll
  for (int i = 0; i < 8; ++i) p[tid + i * 256] = v[i] * inv;
}

// ---- context[b,h] = sum_s attn[b,s]*enc[b,s,h]; grid (16 s-chunks, 64 b), atomics ----
__global__ __launch_bounds__(128) void k_ctx(const float* __restrict__ enc,
                                             const float* __restrict__ attn,
                                             float* __restrict__ ctx) {
  int sc = blockIdx.x, b = blockIdx.y, tid = threadIdx.x;
  float cx = 0, cy = 0, cz = 0, cw = 0;
  const float* wp = attn + b * SS + sc * 128;                 // uniform -> s_load
  const float4* e4 = (const float4*)(enc + ((size_t)b * SS + sc * 128) * HH);
  for (int s = 0; s < 128; ++s) {
    float w = wp[s];
    float4 v = e4[(size_t)s * 128 + tid];
    cx += w * v.x; cy += w * v.y; cz += w * v.z; cw += w * v.w;
  }
  float* cp = ctx + b * HH + tid * 4;
  atomicAdd(cp + 0, cx); atomicAdd(cp + 1, cy);
  atomicAdd(cp + 2, cz); atomicAdd(cp + 3, cw);
}

// ---- GRU r/z gates; grid (64 b, 2 gates), block 512 (h) ----
__global__ __launch_bounds__(512) void k_gates(
    const float* __restrict__ x, const float* __restrict__ ctx,
    const float* __restrict__ hidden,
    const float* __restrict__ Wxr, const float* __restrict__ Wxrb, const float* __restrict__ Whr,
    const float* __restrict__ Wxz, const float* __restrict__ Wxzb, const float* __restrict__ Whz,
    float* __restrict__ r_out, float* __restrict__ z_out, float* __restrict__ rh_out) {
  int b = blockIdx.x, sel = blockIdx.y, h = threadIdx.x;
  const float* Wx = sel ? Wxz : Wxr;
  const float* Wh = sel ? Whz : Whr;
  const float* bias = sel ? Wxzb : Wxrb;
  float acc = bias[h];
  for (int i = 0; i < INDIM; ++i) acc += x[b * INDIM + i] * Wx[i * HH + h];
  for (int j = 0; j < HH; ++j)    acc += ctx[b * HH + j] * Wx[(INDIM + j) * HH + h];
  for (int j = 0; j < HH; ++j)    acc += hidden[b * HH + j] * Wh[j * HH + h];
  float g = fast_sigmoid(acc);
  if (sel == 0) {
    r_out[b * HH + h] = g;
    rh_out[b * HH + h] = g * hidden[b * HH + h];
  } else {
    z_out[b * HH + h] = g;
  }
}

// ---- h_tilde + new_hidden; grid 64, block 512 ----
__global__ __launch_bounds__(512) void k_newh(
    const float* __restrict__ x, const float* __restrict__ ctx,
    const float* __restrict__ Wxh, const float* __restrict__ Wxhb,
    const float* __restrict__ Whh, const float* __restrict__ rh,
    const float* __restrict__ z, const float* __restrict__ hidden,
    float* __restrict__ nh) {
  int b = blockIdx.x, h = threadIdx.x;
  float acc = Wxhb[h];
  for (int i = 0; i < INDIM; ++i) acc += x[b * INDIM + i] * Wxh[i * HH + h];
  for (int j = 0; j < HH; ++j)    acc += ctx[b * HH + j] * Wxh[(INDIM + j) * HH + h];
  for (int j = 0; j < HH; ++j)    acc += rh[b * HH + j] * Whh[j * HH + h];
  float ht = fast_tanh(acc);
  float zz = z[b * HH + h];
  float prev = hidden[b * HH + h];
  nh[b * HH + h] = zz * prev + (1.0f - zz) * ht;
}

// ---- output projection: out[b,o] = nh[b]@Who[:,o] + b[o] ----
// grid (125 o-tiles of 256, 2 h-halves), block 256 = 4 waves; wave = 16-batch group.
// nh reads are wave-uniform (readfirstlane) -> scalar pipe; results via f32 atomics.
__global__ __launch_bounds__(256) void k_out(const float* __restrict__ nh,
                                             const float* __restrict__ Who,
                                             const float* __restrict__ Whob,
                                             float* __restrict__ out) {
  int tid = threadIdx.x;
  int o4 = blockIdx.x * 64 + (tid & 63);               // float4 column index
  int bg = __builtin_amdgcn_readfirstlane(tid >> 6);   // wave-uniform batch group
  int b0 = bg * 16;
  int hbase = blockIdx.y * 256;
  float4 acc[16];
#pragma unroll
  for (int i = 0; i < 16; ++i) acc[i] = make_float4(0.f, 0.f, 0.f, 0.f);
  for (int h = 0; h < 256; ++h) {
    int hh = hbase + h;
    float4 w = *(const float4*)(Who + (size_t)hh * OUTD + o4 * 4);
#pragma unroll
    for (int bb = 0; bb < 16; ++bb) {
      float a = nh[(b0 + bb) * HH + hh];               // s_load
      acc[bb].x += a * w.x; acc[bb].y += a * w.y;
      acc[bb].z += a * w.z; acc[bb].w += a * w.w;
    }
  }
  if (blockIdx.y == 0) {
    float4 bias = *(const float4*)(Whob + o4 * 4);
#pragma unroll
    for (int bb = 0; bb < 16; ++bb) {
      acc[bb].x += bias.x; acc[bb].y += bias.y; acc[bb].z += bias.z; acc[bb].w += bias.w;
    }
  }
#pragma unroll
  for (int bb = 0; bb < 16; ++bb) {
    float* p = out + (size_t)(b0 + bb) * OUTD + o4 * 4;
    atomicAdd(p + 0, acc[bb].x); atomicAdd(p + 1, acc[bb].y);
    atomicAdd(p + 2, acc[bb].z); atomicAdd(p + 3, acc[bb].w);
  }
}

extern "C" void kernel_launch(void* const* d_in, const int* in_sizes, int n_in,
                              void* d_out, int out_size, void* d_ws, size_t ws_size,
                              hipStream_t stream) {
  const float* x    = (const float*)d_in[0];
  const float* hid  = (const float*)d_in[1];
  const float* enc  = (const float*)d_in[2];
  const float* W1w  = (const float*)d_in[3];
  const float* W1b  = (const float*)d_in[4];
  const float* W2w  = (const float*)d_in[5];
  const float* vw   = (const float*)d_in[6];
  const float* Wxr  = (const float*)d_in[7];
  const float* Wxrb = (const float*)d_in[8];
  const float* Whr  = (const float*)d_in[9];
  const float* Wxz  = (const float*)d_in[10];
  const float* Wxzb = (const float*)d_in[11];
  const float* Whz  = (const float*)d_in[12];
  const float* Wxh  = (const float*)d_in[13];
  const float* Wxhb = (const float*)d_in[14];
  const float* Whh  = (const float*)d_in[15];
  const float* Who  = (const float*)d_in[16];
  const float* Whob = (const float*)d_in[17];

  float* out  = (float*)d_out;                    // [64,32000]
  float* nh   = out + (size_t)BB * OUTD;          // [64,512]
  float* attn = nh + (size_t)BB * HH;             // [64,2048] (raw scores then weights)

  char* ws = (char*)d_ws;
  unsigned short* W1t = (unsigned short*)(ws + WS_W1T);
  float* hb  = (float*)(ws + WS_HB);
  float* ctx = (float*)(ws + WS_CTX);
  float* rg  = (float*)(ws + WS_R);
  float* zg  = (float*)(ws + WS_Z);
  float* rh  = (float*)(ws + WS_RH);

  k_prep<<<8000, 256, 0, stream>>>(W1w, W1t, ctx, out);
  k_hb<<<BB, EE, 0, stream>>>(hid, W2w, W1b, hb);
  k_scores<<<(BB * SS) / 128, 512, 0, stream>>>(enc, W1t, hb, vw, attn);
  k_softmax<<<BB, 256, 0, stream>>>(attn);
  k_ctx<<<dim3(16, BB), 128, 0, stream>>>(enc, attn, ctx);
  k_gates<<<dim3(BB, 2), HH, 0, stream>>>(x, ctx, hid, Wxr, Wxrb, Whr, Wxz, Wxzb, Whz,
                                          rg, zg, rh);
  k_newh<<<BB, HH, 0, stream>>>(x, ctx, Wxh, Wxhb, Whh, rh, zg, hid, nh);
  k_out<<<dim3(125, 2), 256, 0, stream>>>(nh, Who, Whob, out);
}

// Round 2
// 679.117 us; speedup vs baseline: 1.2526x; 1.2526x over previous
//
#include <hip/hip_runtime.h>

// Problem dims
#define BB 64
#define SS 2048
#define INDIM 256
#define HH 512
#define EE 256
#define OUTD 32000

typedef __attribute__((ext_vector_type(8))) short short8;
typedef __attribute__((ext_vector_type(4))) float floatx4;

#define LOG2E 1.4426950408889634f

// ---- helpers ----
__device__ __forceinline__ unsigned short f2bf(float f) {
  unsigned u = __float_as_uint(f);
  return (unsigned short)((u + 0x7FFFu + ((u >> 16) & 1u)) >> 16);  // RNE
}
__device__ __forceinline__ unsigned pk2(float a, float b) {
  return (unsigned)f2bf(a) | ((unsigned)f2bf(b) << 16);
}
__device__ __forceinline__ float bf2f(unsigned short u) {
  return __uint_as_float((unsigned)u << 16);
}
__device__ __forceinline__ float fast_tanh(float x) {
  float e = __builtin_amdgcn_exp2f(x * 2.8853900817779268f);
  return 1.0f - 2.0f * __builtin_amdgcn_rcpf(e + 1.0f);
}
__device__ __forceinline__ float fast_sigmoid(float x) {
  float e = __builtin_amdgcn_exp2f(-x * LOG2E);
  return __builtin_amdgcn_rcpf(1.0f + e);
}

// ws layout (bytes)
#define WS_W1T  0         // 256x512 bf16 W1^T              : 262144
#define WS_HB   262144    // 64x256 f32 hidden@W2 + W1_b    : 65536
#define WS_CTX  327680    // 64x512 f32 ctx (unnorm atomic) : 131072
#define WS_NHBF 458752    // 64x512 bf16 new hidden         : 65536
#define WS_SUM  524288    // 64 f32 sum of exp(scores)      : 256
#define WS_Z    589824    // 64x512 f32 update gate         : 131072
#define WS_RH   720896    // 64x512 f32 r*hidden            : 131072

// ---- prep: transpose+convert W1 -> bf16 [e][k]; zero ctx accum + sumexp ----
__global__ void k_prep(const float* __restrict__ W1, unsigned short* __restrict__ W1t,
                       float* __restrict__ ctx, float* __restrict__ sumexp) {
  int idx = blockIdx.x * 256 + threadIdx.x;
  if (idx < HH * EE) {                       // idx = k*256 + e (coalesced read)
    int k = idx >> 8, e = idx & 255;
    W1t[e * HH + k] = f2bf(W1[idx]);
  }
  if (idx < BB * HH) ctx[idx] = 0.0f;
  if (idx < BB) sumexp[idx] = 0.0f;
}

// ---- hb[b][e] = W1_b[e] + hidden[b]@W2[:,e] ----
__global__ void k_hb(const float* __restrict__ hidden, const float* __restrict__ W2,
                     const float* __restrict__ W1b, float* __restrict__ hb) {
  int b = blockIdx.x, e = threadIdx.x;
  float acc = W1b[e];
  for (int h = 0; h < HH; ++h)
    acc += hidden[b * HH + h] * W2[h * EE + e];
  hb[b * EE + e] = acc;
}

// ---- fused scores + exp + unnormalized context ----
// grid 1024 (BS/128), block 512 (8 waves as 2(M) x 4(N)).
// Keeps entire 128x512 enc tile in LDS (bf16) so enc is read from HBM ONCE:
// pass 1: MFMA enc@W1 -> tanh -> score -> w=exp(score) (bounded, no max needed)
// pass 2: ctx_part[h] = sum_row w_row * enc_bf[row][h] from LDS, atomic to ctx.
#define LDA 520   // 512 k + 8 pad shorts: 1040B row, 16B-aligned, 2-way banks (free)
__device__ __forceinline__ void stage_chunk(const float* __restrict__ enc,
                                            unsigned short* __restrict__ Afull,
                                            int m0, int kb, int tid) {
  int k0 = kb * 32;
#pragma unroll
  for (int t = 0; t < 2; ++t) {
    int idx = tid + t * 512;            // 1024 float4 chunks: 128 rows x 8 groups
    int row = idx >> 3, kg = idx & 7;
    float4 f = *(const float4*)(enc + (size_t)(m0 + row) * HH + k0 + kg * 4);
    uint2 w; w.x = pk2(f.x, f.y); w.y = pk2(f.z, f.w);
    *(uint2*)(Afull + row * LDA + k0 + kg * 4) = w;
  }
}

__global__ __launch_bounds__(512) void k_scores(
    const float* __restrict__ enc, const unsigned short* __restrict__ W1t,
    const float* __restrict__ hb, const float* __restrict__ vw,
    float* __restrict__ attn, float* __restrict__ ctx, float* __restrict__ sumexp) {
  __shared__ unsigned short Afull[128 * LDA];   // 133120 B
  __shared__ float hb_s[EE], v_s[EE];
  __shared__ float red[4 * 128];
  __shared__ float wbuf[128];

  int tid = threadIdx.x;
  int m0 = blockIdx.x * 128;
  int b = m0 >> 11;
  int sloc = m0 & (SS - 1);
  if (tid < EE) { hb_s[tid] = hb[b * EE + tid]; v_s[tid] = vw[tid]; }

  int lane = tid & 63, wid = tid >> 6;
  int wm = wid >> 2, wn = wid & 3;
  int l15 = lane & 15, quad = lane >> 4;

  floatx4 acc[4][4];
#pragma unroll
  for (int i = 0; i < 4; ++i)
#pragma unroll
    for (int j = 0; j < 4; ++j) acc[i][j] = (floatx4)0.0f;

  stage_chunk(enc, Afull, m0, 0, tid);
  __syncthreads();

  for (int kb = 0; kb < 16; ++kb) {
    if (kb < 15) stage_chunk(enc, Afull, m0, kb + 1, tid);   // pipelined
    int kk = kb * 32 + quad * 8;
    short8 a[4];
#pragma unroll
    for (int i = 0; i < 4; ++i)
      a[i] = *(const short8*)(Afull + (wm * 64 + i * 16 + l15) * LDA + kk);
#pragma unroll
    for (int j = 0; j < 4; ++j) {
      // B fragment straight from L2-resident W1t (bf16 [e][k])
      short8 bfr = *(const short8*)(W1t + (wn * 64 + j * 16 + l15) * HH + kk);
#pragma unroll
      for (int i = 0; i < 4; ++i)
        acc[i][j] = __builtin_amdgcn_mfma_f32_16x16x32_bf16(a[i], bfr, acc[i][j], 0, 0, 0);
    }
    __syncthreads();
  }

  // score epilogue: score[row] = sum_e tanh(C+hb[e])*v[e]
#pragma unroll
  for (int i = 0; i < 4; ++i)
#pragma unroll
    for (int r = 0; r < 4; ++r) {
      float s = 0.0f;
#pragma unroll
      for (int j = 0; j < 4; ++j) {
        int e = wn * 64 + j * 16 + l15;
        s += fast_tanh(acc[i][j][r] + hb_s[e]) * v_s[e];
      }
#pragma unroll
      for (int off = 1; off < 16; off <<= 1) s += __shfl_xor(s, off, 64);
      if (l15 == 0) red[wn * 128 + wm * 64 + i * 16 + quad * 4 + r] = s;
    }
  __syncthreads();
  if (tid < 128) {
    float sc = red[tid] + red[128 + tid] + red[256 + tid] + red[384 + tid];
    float e = __builtin_amdgcn_exp2f(sc * LOG2E);   // |sc| <= ~13: safe w/o max-sub
    wbuf[tid] = e;
    attn[b * SS + sloc + tid] = e;                  // unnormalized; k_norm divides
  }
  __syncthreads();
  if (tid < 64) {
    float s = wbuf[tid] + wbuf[tid + 64];
#pragma unroll
    for (int off = 1; off < 64; off <<= 1) s += __shfl_xor(s, off, 64);
    if (tid == 0) atomicAdd(sumexp + b, s);
  }

  // pass 2: ctx accumulation from LDS tile (no extra HBM traffic)
  int h = tid;
  float cx = 0.0f;
#pragma unroll 8
  for (int r = 0; r < 128; ++r) cx += wbuf[r] * bf2f(Afull[r * LDA + h]);
  atomicAdd(ctx + b * HH + h, cx);
}

// ---- normalize attn and ctx by sumexp ----
__global__ void k_norm(float* __restrict__ attn, float* __restrict__ ctx,
                       const float* __restrict__ sumexp) {
  int b = blockIdx.x, tid = threadIdx.x;
  float inv = 1.0f / sumexp[b];
#pragma unroll
  for (int i = 0; i < 8; ++i) attn[b * SS + tid + i * 256] *= inv;
#pragma unroll
  for (int i = 0; i < 2; ++i) ctx[b * HH + tid + i * 256] *= inv;
}

// ---- GRU r/z gates; grid (64 b, 2 gates), block 512 (h) ----
__global__ __launch_bounds__(512) void k_gates(
    const float* __restrict__ x, const float* __restrict__ ctx,
    const float* __restrict__ hidden,
    const float* __restrict__ Wxr, const float* __restrict__ Wxrb, const float* __restrict__ Whr,
    const float* __restrict__ Wxz, const float* __restrict__ Wxzb, const float* __restrict__ Whz,
    float* __restrict__ z_out, float* __restrict__ rh_out) {
  int b = blockIdx.x, sel = blockIdx.y, h = threadIdx.x;
  const float* Wx = sel ? Wxz : Wxr;
  const float* Wh = sel ? Whz : Whr;
  const float* bias = sel ? Wxzb : Wxrb;
  float acc = bias[h];
  for (int i = 0; i < INDIM; ++i) acc += x[b * INDIM + i] * Wx[i * HH + h];
  for (int j = 0; j < HH; ++j)    acc += ctx[b * HH + j] * Wx[(INDIM + j) * HH + h];
  for (int j = 0; j < HH; ++j)    acc += hidden[b * HH + j] * Wh[j * HH + h];
  float g = fast_sigmoid(acc);
  if (sel == 0) rh_out[b * HH + h] = g * hidden[b * HH + h];
  else          z_out[b * HH + h] = g;
}

// ---- h_tilde + new_hidden (fp32 out + bf16 copy for out-proj) ----
__global__ __launch_bounds__(512) void k_newh(
    const float* __restrict__ x, const float* __restrict__ ctx,
    const float* __restrict__ Wxh, const float* __restrict__ Wxhb,
    const float* __restrict__ Whh, const float* __restrict__ rh,
    const float* __restrict__ z, const float* __restrict__ hidden,
    float* __restrict__ nh, unsigned short* __restrict__ nhbf) {
  int b = blockIdx.x, h = threadIdx.x;
  float acc = Wxhb[h];
  for (int i = 0; i < INDIM; ++i) acc += x[b * INDIM + i] * Wxh[i * HH + h];
  for (int j = 0; j < HH; ++j)    acc += ctx[b * HH + j] * Wxh[(INDIM + j) * HH + h];
  for (int j = 0; j < HH; ++j)    acc += rh[b * HH + j] * Whh[j * HH + h];
  float ht = fast_tanh(acc);
  float zz = z[b * HH + h];
  float val = zz * hidden[b * HH + h] + (1.0f - zz) * ht;
  nh[b * HH + h] = val;
  nhbf[b * HH + h] = f2bf(val);
}

// ---- output projection via MFMA: out[64,32000] = nh_bf16 @ Who + bias ----
// grid 500, block 256 (4 waves); wave computes 64(M) x 16(N) tile, K=512 full.
// Who (fp32) read exactly once, converted to bf16 in-register. No atomics.
__global__ __launch_bounds__(256) void k_out2(const unsigned short* __restrict__ nhbf,
                                              const float* __restrict__ Who,
                                              const float* __restrict__ Whob,
                                              float* __restrict__ out) {
  int tid = threadIdx.x;
  int lane = tid & 63, w = tid >> 6;
  int l15 = lane & 15, quad = lane >> 4;
  int n = blockIdx.x * 64 + w * 16 + l15;       // output column for this lane

  floatx4 acc[4];
#pragma unroll
  for (int i = 0; i < 4; ++i) acc[i] = (floatx4)0.0f;

  for (int kc = 0; kc < 16; ++kc) {
    int k0 = kc * 32;
    // B fragment: B[k][n], k = quad*8 + j
    float bf[8];
    const float* bp = Who + (size_t)(k0 + quad * 8) * OUTD + n;
#pragma unroll
    for (int j = 0; j < 8; ++j) bf[j] = bp[(size_t)j * OUTD];
    union { unsigned u[4]; short8 v; } bu;
#pragma unroll
    for (int j = 0; j < 4; ++j) bu.u[j] = pk2(bf[2 * j], bf[2 * j + 1]);
    // A fragments: nhbf[m][k], m = i*16 + l15, 8 consecutive k (16B)
#pragma unroll
    for (int i = 0; i < 4; ++i) {
      short8 af = *(const short8*)(nhbf + (i * 16 + l15) * HH + k0 + quad * 8);
      acc[i] = __builtin_amdgcn_mfma_f32_16x16x32_bf16(af, bu.v, acc[i], 0, 0, 0);
    }
  }
  float bias = Whob[n];
#pragma unroll
  for (int i = 0; i < 4; ++i)
#pragma unroll
    for (int r = 0; r < 4; ++r) {
      int m = i * 16 + quad * 4 + r;
      out[(size_t)m * OUTD + n] = acc[i][r] + bias;
    }
}

extern "C" void kernel_launch(void* const* d_in, const int* in_sizes, int n_in,
                              void* d_out, int out_size, void* d_ws, size_t ws_size,
                              hipStream_t stream) {
  const float* x    = (const float*)d_in[0];
  const float* hid  = (const float*)d_in[1];
  const float* enc  = (const float*)d_in[2];
  const float* W1w  = (const float*)d_in[3];
  const float* W1b  = (const float*)d_in[4];
  const float* W2w  = (const float*)d_in[5];
  const float* vw   = (const float*)d_in[6];
  const float* Wxr  = (const float*)d_in[7];
  const float* Wxrb = (const float*)d_in[8];
  const float* Whr  = (const float*)d_in[9];
  const float* Wxz  = (const float*)d_in[10];
  const float* Wxzb = (const float*)d_in[11];
  const float* Whz  = (const float*)d_in[12];
  const float* Wxh  = (const float*)d_in[13];
  const float* Wxhb = (const float*)d_in[14];
  const float* Whh  = (const float*)d_in[15];
  const float* Who  = (const float*)d_in[16];
  const float* Whob = (const float*)d_in[17];

  float* out  = (float*)d_out;                    // [64,32000]
  float* nh   = out + (size_t)BB * OUTD;          // [64,512]
  float* attn = nh + (size_t)BB * HH;             // [64,2048]

  char* ws = (char*)d_ws;
  unsigned short* W1t  = (unsigned short*)(ws + WS_W1T);
  float* hb   = (float*)(ws + WS_HB);
  float* ctx  = (float*)(ws + WS_CTX);
  unsigned short* nhbf = (unsigned short*)(ws + WS_NHBF);
  float* sume = (float*)(ws + WS_SUM);
  float* zg   = (float*)(ws + WS_Z);
  float* rh   = (float*)(ws + WS_RH);

  k_prep<<<512, 256, 0, stream>>>(W1w, W1t, ctx, sume);
  k_hb<<<BB, EE, 0, stream>>>(hid, W2w, W1b, hb);
  k_scores<<<(BB * SS) / 128, 512, 0, stream>>>(enc, W1t, hb, vw, attn, ctx, sume);
  k_norm<<<BB, 256, 0, stream>>>(attn, ctx, sume);
  k_gates<<<dim3(BB, 2), HH, 0, stream>>>(x, ctx, hid, Wxr, Wxrb, Whr, Wxz, Wxzb, Whz,
                                          zg, rh);
  k_newh<<<BB, HH, 0, stream>>>(x, ctx, Wxh, Wxhb, Whh, rh, zg, hid, nh, nhbf);
  k_out2<<<500, 256, 0, stream>>>(nhbf, Who, Whob, out);
}